// Round 7
// baseline (207.447 us; speedup 1.0000x reference)
//
#include <hip/hip_runtime.h>
#include <stdint.h>
#include <stddef.h>

// ---------------------------------------------------------------------------
// MultiHeadAttention (softmax intentionally skipped).  B=4 H=16 L=1024
// out0 = energy = mask ? (Q K^T)/8 : -1e10   [B,H,L,L] f32  (256 MB)
// out1 = energy @ V  -> [B,L,H*64] f32                      (16 MB)
// Round 7:
//   k_convert: q/k/v f32 -> bf16 (restored; R4 fusion was -8us regression)
//   k_wt:      weights f32 -> bf16 transposed
//   k_gemm:    bf16 gload_lds A+B (R3 structure) + Vt epilogue + XCD swizzle
//   k_attn:    256-thr blocks, LDS 32 KB (K staged, P per-wave), V read
//              DIRECT from L2 (no staging), mask cached i32x4 in B2,
//              5 blocks/CU (20 waves), XCD swizzle. No maskpack.
// ---------------------------------------------------------------------------

typedef __attribute__((ext_vector_type(8))) short short8;
typedef __attribute__((ext_vector_type(4))) float f32x4;
typedef __attribute__((ext_vector_type(4))) int i32x4;
typedef __attribute__((ext_vector_type(2))) unsigned int u32x2;

#define MFMA16(a, b, c) __builtin_amdgcn_mfma_f32_16x16x32_bf16(a, b, c, 0, 0, 0)

using gptr_t = const __attribute__((address_space(1))) void*;
using lptr_t = __attribute__((address_space(3))) void*;

#define NEGV -10000000000.0f
#define NEGV_BF16 0xD015u  // f2bf(-1e10)

__device__ __forceinline__ unsigned short f2bf(float f) {
  uint32_t u = __builtin_bit_cast(uint32_t, f);
  u += 0x7FFFu + ((u >> 16) & 1u);  // RNE
  return (unsigned short)(u >> 16);
}

// ---- q/k/v f32 -> bf16, 8 elem/thread --------------------------------------
__global__ __launch_bounds__(256) void k_convert(
    const float* __restrict__ q, const float* __restrict__ k, const float* __restrict__ v,
    unsigned short* __restrict__ oq, unsigned short* __restrict__ ok,
    unsigned short* __restrict__ ov) {
  const int z = blockIdx.z;
  const float* src = z == 0 ? q : z == 1 ? k : v;
  unsigned short* dst = z == 0 ? oq : z == 1 ? ok : ov;
  const size_t idx = ((size_t)blockIdx.x * 256 + threadIdx.x) * 8;
  f32x4 a = *(const f32x4*)(src + idx);
  f32x4 b = *(const f32x4*)(src + idx + 4);
  short8 o;
  o[0] = (short)f2bf(a[0]); o[1] = (short)f2bf(a[1]);
  o[2] = (short)f2bf(a[2]); o[3] = (short)f2bf(a[3]);
  o[4] = (short)f2bf(b[0]); o[5] = (short)f2bf(b[1]);
  o[6] = (short)f2bf(b[2]); o[7] = (short)f2bf(b[3]);
  *(short8*)(dst + idx) = o;
}

// ---- W[k][n] f32 -> Wt[n][k] bf16 (64x64 LDS tile transpose) ---------------
__global__ __launch_bounds__(256) void k_wt(
    const float* __restrict__ wq, const float* __restrict__ wk, const float* __restrict__ wv,
    unsigned short* __restrict__ tq, unsigned short* __restrict__ tk,
    unsigned short* __restrict__ tv) {
  const int z = blockIdx.z;
  const float* src = z == 0 ? wq : z == 1 ? wk : wv;
  unsigned short* dst = z == 0 ? tq : z == 1 ? tk : tv;
  __shared__ unsigned short t[64][65];
  const int n0 = blockIdx.x * 64, k0 = blockIdx.y * 64;
#pragma unroll
  for (int i = 0; i < 16; ++i) {
    const int idx = i * 256 + threadIdx.x;
    const int r = idx >> 6, c = idx & 63;
    t[r][c] = f2bf(src[(size_t)(k0 + r) * 1024 + n0 + c]);
  }
  __syncthreads();
#pragma unroll
  for (int i = 0; i < 16; ++i) {
    const int idx = i * 256 + threadIdx.x;
    const int r = idx >> 6, c = idx & 63;
    dst[(size_t)(n0 + r) * 1024 + k0 + c] = t[c][r];
  }
}

// ---- bf16 GEMM: C[4096][1024] = X[4096][1024] @ Wt^T + bias ----------------
// Flat grid 768, XCD-swizzled: same-A-panel blocks share an XCD L2.
__global__ __launch_bounds__(256) void k_gemm(
    const unsigned short* __restrict__ Xq, const unsigned short* __restrict__ Xk,
    const unsigned short* __restrict__ Xv,
    const unsigned short* __restrict__ Wq, const unsigned short* __restrict__ Wk,
    const unsigned short* __restrict__ Wv,
    const float* __restrict__ bq, const float* __restrict__ bk, const float* __restrict__ bv,
    unsigned short* __restrict__ Cq, unsigned short* __restrict__ Ck,
    unsigned short* __restrict__ Vt) {
  const int bid = blockIdx.x;
  const int wg = (bid & 7) * 96 + (bid >> 3);  // bijective: 768 % 8 == 0
  const int z = wg >> 8, rem = wg & 255;
  const unsigned short* X  = z == 0 ? Xq : z == 1 ? Xk : Xv;
  const unsigned short* Wt = z == 0 ? Wq : z == 1 ? Wk : Wv;
  const float* bias        = z == 0 ? bq : z == 1 ? bk : bv;

  __shared__ unsigned short Ads[128 * 64];
  __shared__ unsigned short Bds[128 * 64];

  const int tid = threadIdx.x;
  const int w = tid >> 6, l = tid & 63;
  const int lr = l & 15, g = l >> 4;
  const int m0 = (rem >> 3) * 128, n0 = (rem & 7) * 128;
  const int wm = (w >> 1) * 64, wn = (w & 1) * 64;
  const int srow = tid >> 3, sslot = tid & 7;

  f32x4 acc[4][4];
#pragma unroll
  for (int mi = 0; mi < 4; ++mi)
#pragma unroll
    for (int ni = 0; ni < 4; ++ni) acc[mi][ni] = (f32x4){0.f, 0.f, 0.f, 0.f};

  for (int kt = 0; kt < 16; ++kt) {
    const int kb = kt * 64;
#pragma unroll
    for (int i = 0; i < 4; ++i) {
      const int row = i * 32 + srow;
      const int scol = ((sslot ^ (row & 7)) << 3);  // inverse-swizzled SOURCE
      const unsigned short* ga = X + (size_t)(m0 + row) * 1024 + kb + scol;
      const unsigned short* gb = Wt + (size_t)(n0 + row) * 1024 + kb + scol;
      __builtin_amdgcn_global_load_lds((gptr_t)ga, (lptr_t)&Ads[(i * 32 + w * 8) * 64], 16, 0, 0);
      __builtin_amdgcn_global_load_lds((gptr_t)gb, (lptr_t)&Bds[(i * 32 + w * 8) * 64], 16, 0, 0);
    }
    __syncthreads();
    short8 afr[4][2], bfr[4][2];
#pragma unroll
    for (int t = 0; t < 4; ++t)
#pragma unroll
      for (int ks = 0; ks < 2; ++ks) {
        const int ra = wm + t * 16 + lr;
        afr[t][ks] = *(const short8*)&Ads[ra * 64 + (((ks * 4 + g) ^ (ra & 7)) << 3)];
        const int rb = wn + t * 16 + lr;
        bfr[t][ks] = *(const short8*)&Bds[rb * 64 + (((ks * 4 + g) ^ (rb & 7)) << 3)];
      }
#pragma unroll
    for (int ks = 0; ks < 2; ++ks)
#pragma unroll
      for (int mi = 0; mi < 4; ++mi)
#pragma unroll
        for (int ni = 0; ni < 4; ++ni)
          acc[mi][ni] = MFMA16(afr[mi][ks], bfr[ni][ks], acc[mi][ni]);
    __syncthreads();
  }

  if (z != 2) {
    unsigned short* C = z == 0 ? Cq : Ck;
#pragma unroll
    for (int mi = 0; mi < 4; ++mi)
#pragma unroll
      for (int ni = 0; ni < 4; ++ni) {
        const int n = n0 + wn + ni * 16 + lr;
        const float bs = bias[n];
        f32x4 a = acc[mi][ni];
#pragma unroll
        for (int r = 0; r < 4; ++r) {
          const int m = m0 + wm + mi * 16 + g * 4 + r;  // C/D row=(lane>>4)*4+reg
          C[(size_t)m * 1024 + n] = f2bf(a[r] + bs);
        }
      }
  } else {
    // V: store transposed Vt[(b*16+h)*64+d][l], 4 consecutive l per lane
#pragma unroll
    for (int mi = 0; mi < 4; ++mi)
#pragma unroll
      for (int ni = 0; ni < 4; ++ni) {
        const int ng = n0 + wn + ni * 16 + lr;
        const int hh = ng >> 6, dd = ng & 63;
        const float bs = bias[ng];
        f32x4 a = acc[mi][ni];
        const int mg = m0 + wm + mi * 16 + g * 4;
        const int bb = mg >> 10, ll = mg & 1023;
        u32x2 pk;
        pk[0] = (uint32_t)f2bf(a[0] + bs) | ((uint32_t)f2bf(a[1] + bs) << 16);
        pk[1] = (uint32_t)f2bf(a[2] + bs) | ((uint32_t)f2bf(a[3] + bs) << 16);
        *(u32x2*)&Vt[(size_t)((bb * 16 + hh) * 64 + dd) * 1024 + ll] = pk;
      }
  }
}

// ---- fused energy + mask + store + P@V -------------------------------------
// 256 thr = 4 waves x 16 q = 64 q/block. Flat grid 1024, XCD-swizzled so the
// 16 blocks sharing one (b,h) land on one XCD (K/V/mask L2-hot).
// LDS: K[128][64] 16K + P 4x[16][128] 16K = 32 KB -> 5 blocks/CU, 20 waves.
// V read directly from global (L2-resident, no staging). Per kt, two
// k-halves: QK^T(half) -> B1 raw-P -> drain -> B2 mask+att+writeback ->
// drain -> PV(half, direct V).
__global__ __launch_bounds__(256, 5) void k_attn(
    const unsigned short* __restrict__ Qb, const unsigned short* __restrict__ Kb,
    const unsigned short* __restrict__ Vt, const int* __restrict__ mask,
    float* __restrict__ att, float* __restrict__ xout) {
  const int bid = blockIdx.x;
  const int wg = (bid & 7) * 128 + (bid >> 3);  // bijective: 1024 % 8 == 0
  const int bh = wg >> 4, qt = wg & 15;
  const int b = bh >> 4, h = bh & 15;
  const int tid = threadIdx.x;
  const int w = tid >> 6, l = tid & 63;
  const int lr = l & 15, g = l >> 4;
  const int q0 = qt * 64 + w * 16;  // wave's 16 q-rows

  __shared__ unsigned short Kl[128 * 64];      // [k][d], XOR-swizzled content
  __shared__ unsigned short Pl[4][16 * 128];   // per-wave [q][k], swizzled
  unsigned short* Pw = Pl[w];

  // Q fragment (B-operand): lane holds q-col = lr, d = ks*32 + g*8 ..+7
  short8 qf[2];
#pragma unroll
  for (int ks = 0; ks < 2; ++ks)
    qf[ks] = *(const short8*)&Qb[(size_t)(b * 1024 + q0 + lr) * 1024 +
                                 h * 64 + ks * 32 + g * 8];

  f32x4 xacc[4];
#pragma unroll
  for (int di = 0; di < 4; ++di) xacc[di] = (f32x4){0.f, 0.f, 0.f, 0.f};

  for (int kt = 0; kt < 8; ++kt) {
    const int kb = kt * 128;
    __syncthreads();  // Kl readers of previous tile done
    // ---- stage K[128][64]: coalesced gload_lds, source pre-swizzled ----
#pragma unroll
    for (int i = 0; i < 4; ++i) {
      const int row = i * 32 + (tid >> 3);
      const int slot = tid & 7;
      const unsigned short* src = Kb + (size_t)(b * 1024 + kb + row) * 1024 +
                                  h * 64 + ((slot ^ (row & 7)) << 3);
      __builtin_amdgcn_global_load_lds((gptr_t)src, (lptr_t)&Kl[(i * 32 + w * 8) * 64], 16, 0, 0);
    }
    __syncthreads();  // drains vmcnt -> Kl visible

#pragma unroll
    for (int hh = 0; hh < 2; ++hh) {
      // ---- mask loads (independent, cached; consumed in B2) ----
      i32x4 mv[4];
#pragma unroll
      for (int p = 0; p < 4; ++p)
        mv[p] = *(const i32x4*)&mask[(size_t)(b * 1024 + q0 + p * 4 + g) * 1024 +
                                     kb + hh * 64 + lr * 4];
      // ---- QK^T half: swapped mfma(K, Q); D col=q(lr), row=k(g*4+r) ----
      f32x4 s[4];
#pragma unroll
      for (int n2 = 0; n2 < 4; ++n2) {
        const int row = (hh * 4 + n2) * 16 + lr;
        f32x4 a = (f32x4){0.f, 0.f, 0.f, 0.f};
#pragma unroll
        for (int ks = 0; ks < 2; ++ks) {
          short8 kf = *(const short8*)&Kl[row * 64 + (((ks * 4 + g) ^ (row & 7)) << 3)];
          a = MFMA16(kf, qf[ks], a);
        }
        s[n2] = a;
      }
      // ---- B1: raw scaled bf16 P scatter ----
#pragma unroll
      for (int n2 = 0; n2 < 4; ++n2) {
        u32x2 pk;
        pk[0] = (uint32_t)f2bf(s[n2][0] * 0.125f) | ((uint32_t)f2bf(s[n2][1] * 0.125f) << 16);
        pk[1] = (uint32_t)f2bf(s[n2][2] * 0.125f) | ((uint32_t)f2bf(s[n2][3] * 0.125f) << 16);
        const int colq = (hh * 4 + n2) * 16 + g * 4;
        *(u32x2*)&Pw[lr * 128 + (colq ^ ((lr & 7) << 3))] = pk;
      }
      asm volatile("s_waitcnt lgkmcnt(0)" ::: "memory");
      __builtin_amdgcn_sched_barrier(0);
      // ---- B2: coalesced mask+expand -> att store; masked P writeback ----
#pragma unroll
      for (int p = 0; p < 4; ++p) {
        const int row = p * 4 + g;
        const int col = hh * 64 + lr * 4;
        const int eb = row * 128 + (col ^ ((row & 7) << 3));
        u32x2 pr = *(const u32x2*)&Pw[eb];
        const uint32_t u0 = pr[0], u1 = pr[1];
        f32x4 e;
        e[0] = mv[p][0] ? __builtin_bit_cast(float, u0 << 16) : NEGV;
        e[1] = mv[p][1] ? __builtin_bit_cast(float, u0 & 0xFFFF0000u) : NEGV;
        e[2] = mv[p][2] ? __builtin_bit_cast(float, u1 << 16) : NEGV;
        e[3] = mv[p][3] ? __builtin_bit_cast(float, u1 & 0xFFFF0000u) : NEGV;
        __builtin_nontemporal_store(
            e, (f32x4*)&att[(size_t)(bh * 1024 + q0 + row) * 1024 + kb + col]);
        u32x2 wb;
        wb[0] = (mv[p][0] ? (u0 & 0xFFFFu) : NEGV_BF16) |
                ((mv[p][1] ? (u0 >> 16) : NEGV_BF16) << 16);
        wb[1] = (mv[p][2] ? (u1 & 0xFFFFu) : NEGV_BF16) |
                ((mv[p][3] ? (u1 >> 16) : NEGV_BF16) << 16);
        *(u32x2*)&Pw[eb] = wb;
      }
      asm volatile("s_waitcnt lgkmcnt(0)" ::: "memory");
      __builtin_amdgcn_sched_barrier(0);
      // ---- PV half: x += P @ V, V direct from global (L2-hot) ----
#pragma unroll
      for (int k2 = 0; k2 < 2; ++k2) {
        const int colk = (hh * 2 + k2) * 32 + g * 8;
        short8 pa = *(const short8*)&Pw[lr * 128 + (colk ^ ((lr & 7) << 3))];
#pragma unroll
        for (int di = 0; di < 4; ++di) {
          short8 vf = *(const short8*)&Vt[(size_t)(bh * 64 + di * 16 + lr) * 1024 +
                                          kb + colk];
          xacc[di] = MFMA16(pa, vf, xacc[di]);
        }
      }
    }
    asm volatile("" ::: "memory");  // keep next-kt P writes after PV reads
  }

#pragma unroll
  for (int di = 0; di < 4; ++di) {
    f32x4 a = xacc[di];
#pragma unroll
    for (int r = 0; r < 4; ++r) {
      const int q = q0 + g * 4 + r;  // D row = q-local, col = d-local
      __builtin_nontemporal_store(
          a[r], &xout[(size_t)(b * 1024 + q) * 1024 + h * 64 + di * 16 + lr]);
    }
  }
}

extern "C" void kernel_launch(void* const* d_in, const int* in_sizes, int n_in,
                              void* d_out, int out_size, void* d_ws, size_t ws_size,
                              hipStream_t stream) {
  (void)in_sizes; (void)n_in; (void)out_size;
  const float* q   = (const float*)d_in[0];
  const float* k   = (const float*)d_in[1];
  const float* v   = (const float*)d_in[2];
  const int* mask  = (const int*)d_in[3];
  const float* wq  = (const float*)d_in[4];
  const float* bq  = (const float*)d_in[5];
  const float* wk  = (const float*)d_in[6];
  const float* bk  = (const float*)d_in[7];
  const float* wv  = (const float*)d_in[8];
  const float* bv  = (const float*)d_in[9];
  float* att = (float*)d_out;
  float* x   = att + (size_t)4 * 16 * 1024 * 1024;

  char* ws = (char*)d_ws;
  const size_t SZX = (size_t)4096 * 1024 * 2;  // 8 MB bf16 [4096][1024]
  const size_t SZW = (size_t)1024 * 1024 * 2;  // 2 MB bf16 [1024][1024]
  if (ws_size < 6 * SZX + 3 * SZW) return;     // 54 MB needed
  unsigned short* Xq  = (unsigned short*)(ws);
  unsigned short* Xk  = (unsigned short*)(ws + SZX);
  unsigned short* Xv  = (unsigned short*)(ws + 2 * SZX);
  unsigned short* Wtq = (unsigned short*)(ws + 3 * SZX);
  unsigned short* Wtk = (unsigned short*)(ws + 3 * SZX + SZW);
  unsigned short* Wtv = (unsigned short*)(ws + 3 * SZX + 2 * SZW);
  unsigned short* Qb  = (unsigned short*)(ws + 3 * SZX + 3 * SZW);
  unsigned short* Kb  = (unsigned short*)(ws + 4 * SZX + 3 * SZW);
  unsigned short* Vt  = (unsigned short*)(ws + 5 * SZX + 3 * SZW);

  k_convert<<<dim3(2048, 1, 3), 256, 0, stream>>>(q, k, v, Xq, Xk, Xv);
  k_wt<<<dim3(16, 16, 3), 256, 0, stream>>>(wq, wk, wv, Wtq, Wtk, Wtv);
  k_gemm<<<dim3(768), 256, 0, stream>>>(Xq, Xk, Xv, Wtq, Wtk, Wtv,
                                        bq, bk, bv, Qb, Kb, Vt);
  k_attn<<<dim3(1024), 256, 0, stream>>>(Qb, Kb, Vt, mask, att, x);
}

// Round 8
// 147.335 us; speedup vs baseline: 1.4080x; 1.4080x over previous
//
#include <hip/hip_runtime.h>
#include <stdint.h>
#include <stddef.h>

// ---------------------------------------------------------------------------
// MultiHeadAttention (softmax intentionally skipped).  B=4 H=16 L=1024
// out0 = energy = mask ? (Q K^T)/8 : -1e10   [B,H,L,L] f32  (256 MB)
// out1 = energy @ V  -> [B,L,H*64] f32                      (16 MB)
// Round 8 = R7 prologue (fast XCD-swizzled gemm + Vt epilogue, 27 us)
//         + R3 k_attn (best measured, ~94 us) + XCD-swizzled flat grid.
// ---------------------------------------------------------------------------

typedef __attribute__((ext_vector_type(8))) short short8;
typedef __attribute__((ext_vector_type(4))) float f32x4;
typedef __attribute__((ext_vector_type(4))) int i32x4;
typedef __attribute__((ext_vector_type(2))) unsigned int u32x2;

#define MFMA16(a, b, c) __builtin_amdgcn_mfma_f32_16x16x32_bf16(a, b, c, 0, 0, 0)

using gptr_t = const __attribute__((address_space(1))) void*;
using lptr_t = __attribute__((address_space(3))) void*;

#define NEGV -10000000000.0f
#define NEGV_BF16 0xD015u  // f2bf(-1e10)

__device__ __forceinline__ unsigned short f2bf(float f) {
  uint32_t u = __builtin_bit_cast(uint32_t, f);
  u += 0x7FFFu + ((u >> 16) & 1u);  // RNE
  return (unsigned short)(u >> 16);
}

// ---- q/k/v f32 -> bf16, 8 elem/thread --------------------------------------
__global__ __launch_bounds__(256) void k_convert(
    const float* __restrict__ q, const float* __restrict__ k, const float* __restrict__ v,
    unsigned short* __restrict__ oq, unsigned short* __restrict__ ok,
    unsigned short* __restrict__ ov) {
  const int z = blockIdx.z;
  const float* src = z == 0 ? q : z == 1 ? k : v;
  unsigned short* dst = z == 0 ? oq : z == 1 ? ok : ov;
  const size_t idx = ((size_t)blockIdx.x * 256 + threadIdx.x) * 8;
  f32x4 a = *(const f32x4*)(src + idx);
  f32x4 b = *(const f32x4*)(src + idx + 4);
  short8 o;
  o[0] = (short)f2bf(a[0]); o[1] = (short)f2bf(a[1]);
  o[2] = (short)f2bf(a[2]); o[3] = (short)f2bf(a[3]);
  o[4] = (short)f2bf(b[0]); o[5] = (short)f2bf(b[1]);
  o[6] = (short)f2bf(b[2]); o[7] = (short)f2bf(b[3]);
  *(short8*)(dst + idx) = o;
}

// ---- W[k][n] f32 -> Wt[n][k] bf16 (64x64 LDS tile transpose) ---------------
__global__ __launch_bounds__(256) void k_wt(
    const float* __restrict__ wq, const float* __restrict__ wk, const float* __restrict__ wv,
    unsigned short* __restrict__ tq, unsigned short* __restrict__ tk,
    unsigned short* __restrict__ tv) {
  const int z = blockIdx.z;
  const float* src = z == 0 ? wq : z == 1 ? wk : wv;
  unsigned short* dst = z == 0 ? tq : z == 1 ? tk : tv;
  __shared__ unsigned short t[64][65];
  const int n0 = blockIdx.x * 64, k0 = blockIdx.y * 64;
#pragma unroll
  for (int i = 0; i < 16; ++i) {
    const int idx = i * 256 + threadIdx.x;
    const int r = idx >> 6, c = idx & 63;
    t[r][c] = f2bf(src[(size_t)(k0 + r) * 1024 + n0 + c]);
  }
  __syncthreads();
#pragma unroll
  for (int i = 0; i < 16; ++i) {
    const int idx = i * 256 + threadIdx.x;
    const int r = idx >> 6, c = idx & 63;
    dst[(size_t)(n0 + r) * 1024 + k0 + c] = t[c][r];
  }
}

// ---- bf16 GEMM: C[4096][1024] = X[4096][1024] @ Wt^T + bias ----------------
// Flat grid 768, XCD-swizzled: same-A-panel blocks share an XCD L2.
__global__ __launch_bounds__(256) void k_gemm(
    const unsigned short* __restrict__ Xq, const unsigned short* __restrict__ Xk,
    const unsigned short* __restrict__ Xv,
    const unsigned short* __restrict__ Wq, const unsigned short* __restrict__ Wk,
    const unsigned short* __restrict__ Wv,
    const float* __restrict__ bq, const float* __restrict__ bk, const float* __restrict__ bv,
    unsigned short* __restrict__ Cq, unsigned short* __restrict__ Ck,
    unsigned short* __restrict__ Vt) {
  const int bid = blockIdx.x;
  const int wg = (bid & 7) * 96 + (bid >> 3);  // bijective: 768 % 8 == 0
  const int z = wg >> 8, rem = wg & 255;
  const unsigned short* X  = z == 0 ? Xq : z == 1 ? Xk : Xv;
  const unsigned short* Wt = z == 0 ? Wq : z == 1 ? Wk : Wv;
  const float* bias        = z == 0 ? bq : z == 1 ? bk : bv;

  __shared__ unsigned short Ads[128 * 64];
  __shared__ unsigned short Bds[128 * 64];

  const int tid = threadIdx.x;
  const int w = tid >> 6, l = tid & 63;
  const int lr = l & 15, g = l >> 4;
  const int m0 = (rem >> 3) * 128, n0 = (rem & 7) * 128;
  const int wm = (w >> 1) * 64, wn = (w & 1) * 64;
  const int srow = tid >> 3, sslot = tid & 7;

  f32x4 acc[4][4];
#pragma unroll
  for (int mi = 0; mi < 4; ++mi)
#pragma unroll
    for (int ni = 0; ni < 4; ++ni) acc[mi][ni] = (f32x4){0.f, 0.f, 0.f, 0.f};

  for (int kt = 0; kt < 16; ++kt) {
    const int kb = kt * 64;
#pragma unroll
    for (int i = 0; i < 4; ++i) {
      const int row = i * 32 + srow;
      const int scol = ((sslot ^ (row & 7)) << 3);  // inverse-swizzled SOURCE
      const unsigned short* ga = X + (size_t)(m0 + row) * 1024 + kb + scol;
      const unsigned short* gb = Wt + (size_t)(n0 + row) * 1024 + kb + scol;
      __builtin_amdgcn_global_load_lds((gptr_t)ga, (lptr_t)&Ads[(i * 32 + w * 8) * 64], 16, 0, 0);
      __builtin_amdgcn_global_load_lds((gptr_t)gb, (lptr_t)&Bds[(i * 32 + w * 8) * 64], 16, 0, 0);
    }
    __syncthreads();
    short8 afr[4][2], bfr[4][2];
#pragma unroll
    for (int t = 0; t < 4; ++t)
#pragma unroll
      for (int ks = 0; ks < 2; ++ks) {
        const int ra = wm + t * 16 + lr;
        afr[t][ks] = *(const short8*)&Ads[ra * 64 + (((ks * 4 + g) ^ (ra & 7)) << 3)];
        const int rb = wn + t * 16 + lr;
        bfr[t][ks] = *(const short8*)&Bds[rb * 64 + (((ks * 4 + g) ^ (rb & 7)) << 3)];
      }
#pragma unroll
    for (int ks = 0; ks < 2; ++ks)
#pragma unroll
      for (int mi = 0; mi < 4; ++mi)
#pragma unroll
        for (int ni = 0; ni < 4; ++ni)
          acc[mi][ni] = MFMA16(afr[mi][ks], bfr[ni][ks], acc[mi][ni]);
    __syncthreads();
  }

  if (z != 2) {
    unsigned short* C = z == 0 ? Cq : Ck;
#pragma unroll
    for (int mi = 0; mi < 4; ++mi)
#pragma unroll
      for (int ni = 0; ni < 4; ++ni) {
        const int n = n0 + wn + ni * 16 + lr;
        const float bs = bias[n];
        f32x4 a = acc[mi][ni];
#pragma unroll
        for (int r = 0; r < 4; ++r) {
          const int m = m0 + wm + mi * 16 + g * 4 + r;  // C/D row=(lane>>4)*4+reg
          C[(size_t)m * 1024 + n] = f2bf(a[r] + bs);
        }
      }
  } else {
    // V: store transposed Vt[(b*16+h)*64+d][l], 4 consecutive l per lane
#pragma unroll
    for (int mi = 0; mi < 4; ++mi)
#pragma unroll
      for (int ni = 0; ni < 4; ++ni) {
        const int ng = n0 + wn + ni * 16 + lr;
        const int hh = ng >> 6, dd = ng & 63;
        const float bs = bias[ng];
        f32x4 a = acc[mi][ni];
        const int mg = m0 + wm + mi * 16 + g * 4;
        const int bb = mg >> 10, ll = mg & 1023;
        u32x2 pk;
        pk[0] = (uint32_t)f2bf(a[0] + bs) | ((uint32_t)f2bf(a[1] + bs) << 16);
        pk[1] = (uint32_t)f2bf(a[2] + bs) | ((uint32_t)f2bf(a[3] + bs) << 16);
        *(u32x2*)&Vt[(size_t)((bb * 16 + hh) * 64 + dd) * 1024 + ll] = pk;
      }
  }
}

// ---- fused energy + mask + store + P@V, block-cooperative LDS --------------
// 512 thr = 8 waves x 16 q = 128 q/block. Flat grid 512, XCD-swizzled:
// each XCD owns 8 complete bh (K/V + mask slice L2-resident; 64 blocks/XCD
// co-resident at 2 blocks/CU). LDS: K[128][64] 16K + V[64][128] 16K +
// P 8x[16][128] 32K = 64 KB.
__global__ __launch_bounds__(512, 4) void k_attn(
    const unsigned short* __restrict__ Qb, const unsigned short* __restrict__ Kb,
    const unsigned short* __restrict__ Vt, const int* __restrict__ mask,
    float* __restrict__ att, float* __restrict__ xout) {
  const int bid = blockIdx.x;
  const int wg = (bid & 7) * 64 + (bid >> 3);  // bijective: 512 % 8 == 0
  const int bh = wg >> 3, qt = wg & 7;
  const int b = bh >> 4, h = bh & 15;
  const int tid = threadIdx.x;
  const int w = tid >> 6, l = tid & 63;
  const int lr = l & 15, g = l >> 4;
  const int q0 = qt * 128 + w * 16;  // wave's 16 q-rows

  __shared__ unsigned short Kl[128 * 64];      // [k][d], XOR-swizzled content
  __shared__ unsigned short Vl[64 * 128];      // [d][k], XOR-swizzled content
  __shared__ unsigned short Pl[8 * 16 * 128];  // per-wave [q][k], swizzled
  unsigned short* Pw = &Pl[w * 16 * 128];

  // Q fragment (B-operand): lane holds q-col = lr, d = ks*32 + g*8 ..+7
  short8 qf[2];
#pragma unroll
  for (int ks = 0; ks < 2; ++ks)
    qf[ks] = *(const short8*)&Qb[(size_t)(b * 1024 + q0 + lr) * 1024 +
                                 h * 64 + ks * 32 + g * 8];

  f32x4 xacc[4];
#pragma unroll
  for (int di = 0; di < 4; ++di) xacc[di] = (f32x4){0.f, 0.f, 0.f, 0.f};

  for (int kt = 0; kt < 8; ++kt) {
    const int kb = kt * 128;
    __syncthreads();  // all waves done reading K/V of previous tile
    // ---- stage K[128][64]: coalesced gload_lds, source pre-swizzled ----
#pragma unroll
    for (int i = 0; i < 2; ++i) {
      const int row = i * 64 + (tid >> 3);
      const int slot = tid & 7;
      const unsigned short* src = Kb + (size_t)(b * 1024 + kb + row) * 1024 +
                                  h * 64 + ((slot ^ (row & 7)) << 3);
      __builtin_amdgcn_global_load_lds((gptr_t)src, (lptr_t)&Kl[(i * 64 + w * 8) * 64], 16, 0, 0);
    }
    // ---- stage V[64][128] from Vt ----
#pragma unroll
    for (int i = 0; i < 2; ++i) {
      const int row = i * 32 + (tid >> 4);
      const int slot = tid & 15;
      const unsigned short* src = Vt + (size_t)(bh * 64 + row) * 1024 + kb +
                                  ((slot ^ (row & 7)) << 3);
      __builtin_amdgcn_global_load_lds((gptr_t)src, (lptr_t)&Vl[(i * 32 + w * 4) * 128], 16, 0, 0);
    }
    __syncthreads();  // drains vmcnt -> staged data visible

    // ---- QK^T: swapped mfma(K, Q); D col=q(lr), row=k(g*4+r) ----
    f32x4 s[8];
#pragma unroll
    for (int ni = 0; ni < 8; ++ni) {
      f32x4 a = (f32x4){0.f, 0.f, 0.f, 0.f};
#pragma unroll
      for (int ks = 0; ks < 2; ++ks) {
        const int row = ni * 16 + lr;
        short8 kf = *(const short8*)&Kl[row * 64 + (((ks * 4 + g) ^ (row & 7)) << 3)];
        a = MFMA16(kf, qf[ks], a);
      }
      s[ni] = a;
    }
    // ---- B1: scatter raw scaled bf16 P into per-wave LDS ----
#pragma unroll
    for (int ni = 0; ni < 8; ++ni) {
      u32x2 pk;
      pk[0] = (uint32_t)f2bf(s[ni][0] * 0.125f) | ((uint32_t)f2bf(s[ni][1] * 0.125f) << 16);
      pk[1] = (uint32_t)f2bf(s[ni][2] * 0.125f) | ((uint32_t)f2bf(s[ni][3] * 0.125f) << 16);
      const int colq = ni * 16 + g * 4;
      *(u32x2*)&Pw[lr * 128 + (colq ^ ((lr & 7) << 3))] = pk;
    }
    asm volatile("s_waitcnt lgkmcnt(0)" ::: "memory");
    __builtin_amdgcn_sched_barrier(0);
    // ---- B2: row-major coalesced repass: mask, att store, P writeback ----
#pragma unroll
    for (int p = 0; p < 8; ++p) {
      const int flat = p * 256 + l * 4;
      const int row = flat >> 7;   // 0..15 (q-local)
      const int col = flat & 127;  // k-local, multiple of 4
      const int eb = row * 128 + (col ^ ((row & 7) << 3));
      u32x2 pr = *(const u32x2*)&Pw[eb];
      i32x4 mv = *(const i32x4*)&mask[(size_t)(b * 1024 + q0 + row) * 1024 + kb + col];
      const uint32_t u0 = pr[0], u1 = pr[1];
      f32x4 e;
      e[0] = mv[0] ? __builtin_bit_cast(float, u0 << 16) : NEGV;
      e[1] = mv[1] ? __builtin_bit_cast(float, u0 & 0xFFFF0000u) : NEGV;
      e[2] = mv[2] ? __builtin_bit_cast(float, u1 << 16) : NEGV;
      e[3] = mv[3] ? __builtin_bit_cast(float, u1 & 0xFFFF0000u) : NEGV;
      __builtin_nontemporal_store(
          e, (f32x4*)&att[(size_t)(bh * 1024 + q0 + row) * 1024 + kb + col]);
      u32x2 wb;
      wb[0] = (mv[0] ? (u0 & 0xFFFFu) : NEGV_BF16) |
              ((mv[1] ? (u0 >> 16) : NEGV_BF16) << 16);
      wb[1] = (mv[2] ? (u1 & 0xFFFFu) : NEGV_BF16) |
              ((mv[3] ? (u1 >> 16) : NEGV_BF16) << 16);
      *(u32x2*)&Pw[eb] = wb;
    }
    asm volatile("s_waitcnt lgkmcnt(0)" ::: "memory");
    __builtin_amdgcn_sched_barrier(0);
    // ---- PV: x += P @ V ----
#pragma unroll
    for (int ks4 = 0; ks4 < 4; ++ks4) {
      const int colk = ks4 * 32 + g * 8;
      short8 pa = *(const short8*)&Pw[lr * 128 + (colk ^ ((lr & 7) << 3))];
#pragma unroll
      for (int di = 0; di < 4; ++di) {
        const int vr = di * 16 + lr;
        short8 vf = *(const short8*)&Vl[vr * 128 + (colk ^ ((vr & 7) << 3))];
        xacc[di] = MFMA16(pa, vf, xacc[di]);
      }
    }
    asm volatile("" ::: "memory");  // keep next-iter writes after these reads
  }

#pragma unroll
  for (int di = 0; di < 4; ++di) {
    f32x4 a = xacc[di];
#pragma unroll
    for (int r = 0; r < 4; ++r) {
      const int q = q0 + g * 4 + r;  // D row = q-local, col = d-local
      __builtin_nontemporal_store(
          a[r], &xout[(size_t)(b * 1024 + q) * 1024 + h * 64 + di * 16 + lr]);
    }
  }
}

extern "C" void kernel_launch(void* const* d_in, const int* in_sizes, int n_in,
                              void* d_out, int out_size, void* d_ws, size_t ws_size,
                              hipStream_t stream) {
  (void)in_sizes; (void)n_in; (void)out_size;
  const float* q   = (const float*)d_in[0];
  const float* k   = (const float*)d_in[1];
  const float* v   = (const float*)d_in[2];
  const int* mask  = (const int*)d_in[3];
  const float* wq  = (const float*)d_in[4];
  const float* bq  = (const float*)d_in[5];
  const float* wk  = (const float*)d_in[6];
  const float* bk  = (const float*)d_in[7];
  const float* wv  = (const float*)d_in[8];
  const float* bv  = (const float*)d_in[9];
  float* att = (float*)d_out;
  float* x   = att + (size_t)4 * 16 * 1024 * 1024;

  char* ws = (char*)d_ws;
  const size_t SZX = (size_t)4096 * 1024 * 2;  // 8 MB bf16 [4096][1024]
  const size_t SZW = (size_t)1024 * 1024 * 2;  // 2 MB bf16 [1024][1024]
  if (ws_size < 6 * SZX + 3 * SZW) return;     // 54 MB needed
  unsigned short* Xq  = (unsigned short*)(ws);
  unsigned short* Xk  = (unsigned short*)(ws + SZX);
  unsigned short* Xv  = (unsigned short*)(ws + 2 * SZX);
  unsigned short* Wtq = (unsigned short*)(ws + 3 * SZX);
  unsigned short* Wtk = (unsigned short*)(ws + 3 * SZX + SZW);
  unsigned short* Wtv = (unsigned short*)(ws + 3 * SZX + 2 * SZW);
  unsigned short* Qb  = (unsigned short*)(ws + 3 * SZX + 3 * SZW);
  unsigned short* Kb  = (unsigned short*)(ws + 4 * SZX + 3 * SZW);
  unsigned short* Vt  = (unsigned short*)(ws + 5 * SZX + 3 * SZW);

  k_convert<<<dim3(2048, 1, 3), 256, 0, stream>>>(q, k, v, Xq, Xk, Xv);
  k_wt<<<dim3(16, 16, 3), 256, 0, stream>>>(wq, wk, wv, Wtq, Wtk, Wtv);
  k_gemm<<<dim3(768), 256, 0, stream>>>(Xq, Xk, Xv, Wtq, Wtk, Wtv,
                                        bq, bk, bv, Qb, Kb, Vt);
  k_attn<<<dim3(512), 512, 0, stream>>>(Qb, Kb, Vt, mask, att, x);
}